// Round 12
// baseline (1066.790 us; speedup 1.0000x reference)
//
#include <hip/hip_runtime.h>

typedef unsigned short u16;
typedef unsigned int   u32;
typedef __attribute__((ext_vector_type(8))) short bf16x8;
typedef __attribute__((ext_vector_type(4))) float f32x4;

#define B_ROWS 32768
#define EPS_BN 1e-5f

// ---------- helpers ----------
__device__ __forceinline__ u16 f2bf(float f) {
  u32 u = __float_as_uint(f);
  u32 r = (u + 0x7FFFu + ((u >> 16) & 1u)) >> 16;   // RNE, no NaN inputs
  return (u16)r;
}
__device__ __forceinline__ float bf2f(u16 h) {
  return __uint_as_float(((u32)h) << 16);
}

// GENUINE numpy-fp32 emulation — contraction disabled (critical fix, R9):
//   sp = RN(RN(px^2)+RN(py^2)); sm = RN(RN(mx^2)+RN(my^2))   [no fma]
//   dot = fma(py,my, RN(px*mx));  d2 = RN(RN(sp+sm) - 2*dot)
__device__ __forceinline__ float dcalc(float px, float py, float sp, float mx, float my) {
#pragma clang fp contract(off)
  float sm   = mx * mx + my * my;
  float pm   = px * mx;
  float dot  = __builtin_fmaf(py, my, pm);
  float spsm = sp + sm;
  return spsm - 2.0f * dot;
}
__device__ __forceinline__ float spcalc(float px, float py) {
#pragma clang fp contract(off)
  return px * px + py * py;
}
#define MED3 __builtin_amdgcn_fmed3f

// ---------- KNN: 16 threads/query, 2048 blocks ----------
// pass1: per-slice exact top-4 VALUES (4-deep med3 chains) -> T_est(query) =
// 16th smallest of 64 retained values (>= true T, provably). pass2: collect
// candidates d<=T_est (u16 idx). final: 1 thread/query exact stable top-16.
__global__ __launch_bounds__(256, 8)
void knn_kernel(const float2* __restrict__ pos, const float2* __restrict__ mc,
                const float2* __restrict__ mv, float* __restrict__ knn_out,
                u16* __restrict__ X0)
{
  __shared__ u16 bufC[256 * 32];      // 16 KB candidate store (overlaid tv/tst in phase 1)
  __shared__ u16 cntS[256];           // per-slice candidate counts

  const int t = threadIdx.x;
  const int qloc = t & 15;
  const int slice = t >> 4;
  const int q = blockIdx.x * 16 + qloc;
  const float2 p = pos[q];
  const float sp = spcalc(p.x, p.y);
  const float4* mc4 = (const float4*)mc;
  const int b4 = slice * 256;         // 256 float4 = 512 points per slice
  const int base = slice * 512;

  float* tv  = (float*)bufC;          // [1024] retained values (phase 1 overlay)
  float* tst = tv + 1024;             // [16] per-query thresholds

  // ---- pass 1: two interleaved 4-deep med3 chains (exact slice top-4 values)
  float dA0 = __builtin_inff(), dA1 = dA0, dA2 = dA0, dA3 = dA0;
  float dB0 = dA0, dB1 = dA0, dB2 = dA0, dB3 = dA0;
  float4 cur = mc4[b4];
  for (int i = 0; i < 256; ++i) {
    float4 nxt = mc4[b4 + ((i + 1) & 255)];   // depth-1 prefetch
    float d0 = dcalc(p.x, p.y, sp, cur.x, cur.y);
    float d1 = dcalc(p.x, p.y, sp, cur.z, cur.w);
    dA3 = MED3(dA2, d0, dA3); dA2 = MED3(dA1, d0, dA2);
    dA1 = MED3(dA0, d0, dA1); dA0 = fminf(dA0, d0);
    dB3 = MED3(dB2, d1, dB3); dB2 = MED3(dB1, d1, dB2);
    dB1 = MED3(dB0, d1, dB1); dB0 = fminf(dB0, d1);
    cur = nxt;
  }
  // exact 4 smallest of union of two sorted-4 lists (selection identity)
  float s0 = fminf(dA0, dB0);
  float s1 = fminf(fminf(dA1, dB1), fmaxf(dA0, dB0));
  float s2 = fminf(fminf(dA2, dB2), fminf(fmaxf(dA1, dB0), fmaxf(dA0, dB1)));
  float s3 = fminf(fminf(dA3, dB3),
                   fminf(fmaxf(dA2, dB0), fminf(fmaxf(dA1, dB1), fmaxf(dA0, dB2))));
  tv[t * 4 + 0] = s0; tv[t * 4 + 1] = s1; tv[t * 4 + 2] = s2; tv[t * 4 + 3] = s3;
  __syncthreads();

  // ---- T_est per query: exact 16th smallest of 64 retained values
  if (t < 16) {
    float ch[16];
#pragma unroll
    for (int j = 0; j < 16; ++j) ch[j] = __builtin_inff();
    for (int s = 0; s < 16; ++s) {
#pragma unroll
      for (int j2 = 0; j2 < 4; ++j2) {
        float v = tv[(s * 16 + t) * 4 + j2];
#pragma unroll
        for (int k = 15; k >= 1; --k) ch[k] = MED3(ch[k-1], v, ch[k]);
        ch[0] = fminf(ch[0], v);
      }
    }
    tst[t] = ch[15];
  }
  __syncthreads();
  const float Tq = tst[qloc];
  __syncthreads();                    // tv/tst reads done before bufC overlay

  // ---- pass 2: collect candidate indices with d <= Tq (superset of top-16)
  int cnt = 0;
  for (int i = 0; i < 256; ++i) {
    float4 c2 = mc4[b4 + i];
    float d0 = dcalc(p.x, p.y, sp, c2.x, c2.y);
    float d1 = dcalc(p.x, p.y, sp, c2.z, c2.w);
    if (d0 <= Tq) { if (cnt < 32) bufC[t * 32 + cnt] = (u16)(base + 2 * i);     ++cnt; }
    if (d1 <= Tq) { if (cnt < 32) bufC[t * 32 + cnt] = (u16)(base + 2 * i + 1); ++cnt; }
  }
  cntS[t] = (u16)((cnt > 32) ? 32 : cnt);
  __syncthreads();

  // ---- final: 1 thread/query, exact stable (d asc, idx asc) top-16
  if (t < 16) {                       // qloc == t, p/sp already correct
    float fd[16]; int fi[16];
#pragma unroll
    for (int j = 0; j < 16; ++j) { fd[j] = __builtin_inff(); fi[j] = 0; }
    for (int s = 0; s < 16; ++s) {    // slices in ascending base-index order
      const int th = s * 16 + t;
      const int c = cntS[th];
      for (int j = 0; j < c; ++j) {   // within slice: ascending index order
        int ci = bufC[th * 32 + j];
        float2 m = mc[ci];
        float d = dcalc(p.x, p.y, sp, m.x, m.y);
        if (d < fd[15]) {             // strict <: equal d keeps earlier index
          bool cc = true;
#pragma unroll
          for (int k = 15; k >= 1; --k) {
            bool cm = d < fd[k-1];
            if (cc) {
              if (cm) { fd[k] = fd[k-1]; fi[k] = fi[k-1]; }
              else    { fd[k] = d;       fi[k] = ci;      }
            }
            cc = cm;
          }
          if (cc) { fd[0] = d; fi[0] = ci; }
        }
      }
    }
    float* orow = knn_out + (size_t)q * 66;   // fp32 output 1 (knn_feat)
    u16*   xrow = X0 + (size_t)q * 96;        // bf16 MLP input, Kpad=96
    orow[0] = p.x; orow[1] = p.y;
    xrow[0] = f2bf(p.x); xrow[1] = f2bf(p.y);
#pragma unroll
    for (int j = 0; j < 16; ++j) {
      int ci = fi[j];
      float2 m = mc[ci], v = mv[ci];
      orow[2 + 4*j + 0] = m.x; orow[2 + 4*j + 1] = m.y;
      orow[2 + 4*j + 2] = v.x; orow[2 + 4*j + 3] = v.y;
      xrow[2 + 4*j + 0] = f2bf(m.x); xrow[2 + 4*j + 1] = f2bf(m.y);
      xrow[2 + 4*j + 2] = f2bf(v.x); xrow[2 + 4*j + 3] = f2bf(v.y);
    }
#pragma unroll
    for (int c = 66; c < 96; ++c) xrow[c] = 0;
  }
}

// ---------- weight prep: fp32 [K][N] -> bf16 transposed [N][Kpad] ----------
__global__ __launch_bounds__(256)
void prep_wt_all(const float* __restrict__ w1, const float* __restrict__ w2,
                 const float* __restrict__ w3, const float* __restrict__ w4,
                 const float* __restrict__ w5,
                 u16* __restrict__ wt1, u16* __restrict__ wt2, u16* __restrict__ wt3,
                 u16* __restrict__ wt4, u16* __restrict__ wt5)
{
  const int l = blockIdx.y;
  const float* w; u16* wt; int K, N, Kp;
  if (l == 0)      { w = w1; wt = wt1; K = 66;  N = 128; Kp = 96;  }
  else if (l == 1) { w = w2; wt = wt2; K = 128; N = 256; Kp = 128; }
  else if (l == 2) { w = w3; wt = wt3; K = 256; N = 512; Kp = 256; }
  else if (l == 3) { w = w4; wt = wt4; K = 512; N = 128; Kp = 512; }
  else             { w = w5; wt = wt5; K = 128; N = 64;  Kp = 128; }
  int i = blockIdx.x * 256 + threadIdx.x;
  if (i >= N * Kp) return;
  int n = i / Kp, kp = i - n * Kp;
  float v = (kp < K) ? w[(size_t)kp * N + n] : 0.0f;
  wt[i] = f2bf(v);
}

// ---------- GEMM (bf16 MFMA) + optional fused BN+ReLU on A + bias + stats ----------
template<int BN, bool FUSE>
__global__ __launch_bounds__(256)
void gemm_bn_kernel(const u16* __restrict__ X, int Kw,
                    const u16* __restrict__ WT,
                    const float* __restrict__ bias,
                    const float* __restrict__ psum, const float* __restrict__ psq,
                    const float* __restrict__ gw,   const float* __restrict__ bw,
                    u16* __restrict__ Z, int N,
                    float* __restrict__ csum, float* __restrict__ csq)
{
  constexpr int BM = 128;
  constexpr int AST = 40;                 // 32 data + 8 pad (bf16)
  __shared__ u16 Ash[BM * AST];
  __shared__ u16 Bsh[BN * AST];
  __shared__ float redS[4][128];
  __shared__ float redQ[4][128];
  __shared__ float scA[512];
  __shared__ float ttA[512];

  const int t = threadIdx.x;
  const int wave = t >> 6;
  const int lane = t & 63;
  const int lr = lane & 15;
  const int qd = lane >> 4;
  const int m0 = blockIdx.x * BM;
  const int n0 = blockIdx.y * BN;

  if (FUSE) {
    const float invB = 1.0f / 32768.0f;
    for (int c = t; c < Kw; c += 256) {
      float mean = psum[c] * invB;
      float var  = __fmaf_rn(-mean, mean, psq[c] * invB);  // biased
      float sc   = gw[c] * rsqrtf(var + EPS_BN);
      scA[c] = sc;
      ttA[c] = __fmaf_rn(-mean, sc, bw[c]);
    }
    __syncthreads();
  }

  f32x4 acc[2][BN / 16];
#pragma unroll
  for (int a = 0; a < 2; ++a)
#pragma unroll
    for (int b = 0; b < BN / 16; ++b) {
      acc[a][b][0] = 0.f; acc[a][b][1] = 0.f; acc[a][b][2] = 0.f; acc[a][b][3] = 0.f;
    }

  const int sr = t >> 2;          // 0..63
  const int sk = (t & 3) * 8;     // 0,8,16,24

  for (int k0 = 0; k0 < Kw; k0 += 32) {
#pragma unroll
    for (int rr = 0; rr < 2; ++rr) {
      int r = sr + rr * 64;
      uint4 g = *(const uint4*)(&X[(size_t)(m0 + r) * Kw + k0 + sk]);
      if (FUSE) {
        u32 w[4] = {g.x, g.y, g.z, g.w};
        u32 o[4];
#pragma unroll
        for (int e = 0; e < 4; ++e) {
          int kk = k0 + sk + 2 * e;
          float lo = bf2f((u16)(w[e] & 0xffffu));
          float hi = bf2f((u16)(w[e] >> 16));
          float yl = fmaxf(__fmaf_rn(lo, scA[kk],     ttA[kk]),     0.0f);
          float yh = fmaxf(__fmaf_rn(hi, scA[kk + 1], ttA[kk + 1]), 0.0f);
          o[e] = (u32)f2bf(yl) | ((u32)f2bf(yh) << 16);
        }
        g.x = o[0]; g.y = o[1]; g.z = o[2]; g.w = o[3];
      }
      *(uint4*)(&Ash[r * AST + sk]) = g;
    }
#pragma unroll
    for (int rr = 0; rr < BN / 64; ++rr) {
      int n = sr + rr * 64;
      *(uint4*)(&Bsh[n * AST + sk]) =
          *(const uint4*)(&WT[(size_t)(n0 + n) * Kw + k0 + sk]);
    }
    __syncthreads();
    bf16x8 af0 = *(const bf16x8*)(&Ash[(wave * 32 + lr) * AST + qd * 8]);
    bf16x8 af1 = *(const bf16x8*)(&Ash[(wave * 32 + 16 + lr) * AST + qd * 8]);
#pragma unroll
    for (int ct = 0; ct < BN / 16; ++ct) {
      bf16x8 bfr = *(const bf16x8*)(&Bsh[(ct * 16 + lr) * AST + qd * 8]);
      acc[0][ct] = __builtin_amdgcn_mfma_f32_16x16x32_bf16(af0, bfr, acc[0][ct], 0, 0, 0);
      acc[1][ct] = __builtin_amdgcn_mfma_f32_16x16x32_bf16(af1, bfr, acc[1][ct], 0, 0, 0);
    }
    __syncthreads();
  }

  // epilogue: bias, bf16 Z store, per-column partial sums
#pragma unroll
  for (int ct = 0; ct < BN / 16; ++ct) {
    int cg = n0 + ct * 16 + lr;
    float bv = bias[cg];
    float s = 0.f, sqv = 0.f;
#pragma unroll
    for (int rt = 0; rt < 2; ++rt) {
#pragma unroll
      for (int r = 0; r < 4; ++r) {
        float z = acc[rt][ct][r] + bv;
        int row = m0 + wave * 32 + rt * 16 + qd * 4 + r;  // C/D: row=quad*4+reg, col=lane&15
        Z[(size_t)row * N + cg] = f2bf(z);
        s += z;
        sqv = __fmaf_rn(z, z, sqv);
      }
    }
    s   += __shfl_xor(s, 16);   s   += __shfl_xor(s, 32);
    sqv += __shfl_xor(sqv, 16); sqv += __shfl_xor(sqv, 32);
    if (qd == 0) { redS[wave][ct * 16 + lr] = s; redQ[wave][ct * 16 + lr] = sqv; }
  }
  __syncthreads();
  if (t < BN) {
    float s  = redS[0][t] + redS[1][t] + redS[2][t] + redS[3][t];
    float sv = redQ[0][t] + redQ[1][t] + redQ[2][t] + redQ[3][t];
    atomicAdd(&csum[n0 + t], s);
    atomicAdd(&csq[n0 + t], sv);
  }
}

// ---------- final layer: fused BN5+ReLU + 64->2 GEMV, fp32 out ----------
__global__ __launch_bounds__(256)
void gemv6_kernel(const u16* __restrict__ Z5, const float* __restrict__ w6,
                  const float* __restrict__ b6,
                  const float* __restrict__ psum, const float* __restrict__ psq,
                  const float* __restrict__ gw,   const float* __restrict__ bw,
                  float* __restrict__ out)
{
  __shared__ float wsh[128];
  __shared__ float scs[64];
  __shared__ float tts[64];
  const int t = threadIdx.x;
  if (t < 128) wsh[t] = w6[t];
  if (t < 64) {
    const float invB = 1.0f / 32768.0f;
    float mean = psum[t] * invB;
    float var  = __fmaf_rn(-mean, mean, psq[t] * invB);
    float sc   = gw[t] * rsqrtf(var + EPS_BN);
    scs[t] = sc;
    tts[t] = __fmaf_rn(-mean, sc, bw[t]);
  }
  __syncthreads();
  const int q = blockIdx.x * 256 + t;
  const uint4* xv = (const uint4*)(Z5 + (size_t)q * 64);
  float a0 = 0.f, a1 = 0.f;
#pragma unroll
  for (int cc = 0; cc < 8; ++cc) {
    uint4 pk = xv[cc];
    u32 u[4] = {pk.x, pk.y, pk.z, pk.w};
#pragma unroll
    for (int uu = 0; uu < 4; ++uu) {
      int k = cc * 8 + uu * 2;
      float z0 = bf2f((u16)(u[uu] & 0xffffu));
      float z1 = bf2f((u16)(u[uu] >> 16));
      float x0 = fmaxf(__fmaf_rn(z0, scs[k],     tts[k]),     0.0f);
      float x1 = fmaxf(__fmaf_rn(z1, scs[k + 1], tts[k + 1]), 0.0f);
      x0 = bf2f(f2bf(x0));  // match prior bf16 round-trip of activations
      x1 = bf2f(f2bf(x1));
      a0 = __fmaf_rn(x0, wsh[2 * k + 0], a0);
      a1 = __fmaf_rn(x0, wsh[2 * k + 1], a1);
      a0 = __fmaf_rn(x1, wsh[2 * k + 2], a0);
      a1 = __fmaf_rn(x1, wsh[2 * k + 3], a1);
    }
  }
  float2 o; o.x = a0 + b6[0]; o.y = a1 + b6[1];
  ((float2*)out)[q] = o;
}

// ---------- launch ----------
extern "C" void kernel_launch(void* const* d_in, const int* in_sizes, int n_in,
                              void* d_out, int out_size, void* d_ws, size_t ws_size,
                              hipStream_t stream)
{
  const float2* pos = (const float2*)d_in[0];
  const float2* mc  = (const float2*)d_in[1];
  const float2* mv  = (const float2*)d_in[2];
  const float* w1 = (const float*)d_in[3];  const float* b1 = (const float*)d_in[4];
  const float* w2 = (const float*)d_in[5];  const float* b2 = (const float*)d_in[6];
  const float* w3 = (const float*)d_in[7];  const float* b3 = (const float*)d_in[8];
  const float* w4 = (const float*)d_in[9];  const float* b4 = (const float*)d_in[10];
  const float* w5 = (const float*)d_in[11]; const float* b5 = (const float*)d_in[12];
  const float* w6 = (const float*)d_in[13]; const float* b6 = (const float*)d_in[14];
  const float* g1 = (const float*)d_in[15]; const float* be1 = (const float*)d_in[16];
  const float* g2 = (const float*)d_in[17]; const float* be2 = (const float*)d_in[18];
  const float* g3 = (const float*)d_in[19]; const float* be3 = (const float*)d_in[20];
  const float* g4 = (const float*)d_in[21]; const float* be4 = (const float*)d_in[22];
  const float* g5 = (const float*)d_in[23]; const float* be5 = (const float*)d_in[24];

  // ws layout (bf16): X0 6.29MB | ZA 33.55MB | ZB 33.55MB | WT1..5 | stats
  char* ws = (char*)d_ws;
  u16* X0   = (u16*)(ws + 0);
  u16* ZA   = (u16*)(ws + 6291456);
  u16* ZB   = (u16*)(ws + 39845888);
  u16* WT1  = (u16*)(ws + 73400320);
  u16* WT2  = (u16*)(ws + 73424896);
  u16* WT3  = (u16*)(ws + 73490432);
  u16* WT4  = (u16*)(ws + 73752576);
  u16* WT5  = (u16*)(ws + 73883648);
  float* stats = (float*)(ws + 73900032);
  float* s1 = stats;        float* s2 = stats + 128;  float* s3 = stats + 384;
  float* s4 = stats + 896;  float* s5 = stats + 1024;
  float* sqb = stats + 1088;
  float* q1 = sqb;          float* q2 = sqb + 128;    float* q3 = sqb + 384;
  float* q4 = sqb + 896;    float* q5 = sqb + 1024;

  float* outX = (float*)d_out;
  float* outK = outX + 2 * B_ROWS;

  hipMemsetAsync(stats, 0, 2176 * sizeof(float), stream);
  prep_wt_all<<<dim3(512, 5), 256, 0, stream>>>(w1, w2, w3, w4, w5, WT1, WT2, WT3, WT4, WT5);
  knn_kernel<<<dim3(2048), 256, 0, stream>>>(pos, mc, mv, outK, X0);

  gemm_bn_kernel<128, false><<<dim3(256, 1), 256, 0, stream>>>(
      X0, 96, WT1, b1, nullptr, nullptr, nullptr, nullptr, ZA, 128, s1, q1);
  gemm_bn_kernel<128, true><<<dim3(256, 2), 256, 0, stream>>>(
      ZA, 128, WT2, b2, s1, q1, g1, be1, ZB, 256, s2, q2);
  gemm_bn_kernel<128, true><<<dim3(256, 4), 256, 0, stream>>>(
      ZB, 256, WT3, b3, s2, q2, g2, be2, ZA, 512, s3, q3);
  gemm_bn_kernel<128, true><<<dim3(256, 1), 256, 0, stream>>>(
      ZA, 512, WT4, b4, s3, q3, g3, be3, ZB, 128, s4, q4);
  gemm_bn_kernel<64, true><<<dim3(256, 1), 256, 0, stream>>>(
      ZB, 128, WT5, b5, s4, q4, g4, be4, ZA, 64, s5, q5);
  gemv6_kernel<<<dim3(128), 256, 0, stream>>>(ZA, w6, b6, s5, q5, g5, be5, outX);

  (void)in_sizes; (void)n_in; (void)out_size; (void)ws_size;
}

// Round 13
// 364.129 us; speedup vs baseline: 2.9297x; 2.9297x over previous
//
#include <hip/hip_runtime.h>

typedef unsigned short u16;
typedef unsigned int   u32;
typedef __attribute__((ext_vector_type(8))) short bf16x8;
typedef __attribute__((ext_vector_type(4))) float f32x4;

#define B_ROWS 32768
#define EPS_BN 1e-5f

// ---------- helpers ----------
__device__ __forceinline__ u16 f2bf(float f) {
  u32 u = __float_as_uint(f);
  u32 r = (u + 0x7FFFu + ((u >> 16) & 1u)) >> 16;   // RNE, no NaN inputs
  return (u16)r;
}
__device__ __forceinline__ float bf2f(u16 h) {
  return __uint_as_float(((u32)h) << 16);
}

// GENUINE numpy-fp32 emulation — contraction disabled (critical fix, R9):
//   sp = RN(RN(px^2)+RN(py^2)); sm = RN(RN(mx^2)+RN(my^2))   [no fma]
//   dot = fma(py,my, RN(px*mx));  d2 = RN(RN(sp+sm) - 2*dot)
__device__ __forceinline__ float dcalc(float px, float py, float sp, float mx, float my) {
#pragma clang fp contract(off)
  float sm   = mx * mx + my * my;
  float pm   = px * mx;
  float dot  = __builtin_fmaf(py, my, pm);
  float spsm = sp + sm;
  return spsm - 2.0f * dot;
}
// same bits, with sm precomputed once per point (sm expression identical)
__device__ __forceinline__ float dcalc2(float px, float py, float sp, float mx, float my,
                                        float sm) {
#pragma clang fp contract(off)
  float pm   = px * mx;
  float dot  = __builtin_fmaf(py, my, pm);
  float spsm = sp + sm;
  return spsm - 2.0f * dot;
}
__device__ __forceinline__ float smcalc(float mx, float my) {
#pragma clang fp contract(off)
  return mx * mx + my * my;
}
__device__ __forceinline__ float spcalc(float px, float py) {
#pragma clang fp contract(off)
  return px * px + py * py;
}
#define MED3 __builtin_amdgcn_fmed3f

// ---------- KNN: 32 queries/block, 8 queries/thread x 128-pt slice ----------
// pass1: per-(query,slice) exact top-2 values (med3 chain) -> T_est(q) = exact
// 16th of 128 retained (>= true 16th, since retained subset of values).
// pass2: collect candidates d<=T_est into per-query LDS lists (atomic append).
// final: 1 thread/query, exact (d, idx)-lexicographic top-16.
__global__ __launch_bounds__(256, 4)
void knn_kernel(const float2* __restrict__ pos, const float2* __restrict__ mc,
                const float2* __restrict__ mv, float* __restrict__ knn_out,
                u16* __restrict__ X0)
{
  __shared__ float tv[32 * 130];      // 16.6 KB retained values [q][s*2+v], pad->130
  __shared__ float tstS[32];
  __shared__ int   qcnt[32];

  const int t = threadIdx.x;
  const int g = t >> 6;               // wave = query group (8 queries)
  const int s = t & 63;               // slice id: 128 points
  const int q0 = blockIdx.x * 32;

  float px[8], py[8], sp[8];
#pragma unroll
  for (int j = 0; j < 8; ++j) {
    float2 p = pos[q0 + g * 8 + j];
    px[j] = p.x; py[j] = p.y; sp[j] = spcalc(p.x, p.y);
  }

  const float4* mc4 = (const float4*)mc;
  const int b4 = s * 64;              // 64 float4 = 128 points
  const int basePt = s * 128;

  // ---- pass 1: top-2 chain per query
  float z0[8], z1[8];
#pragma unroll
  for (int j = 0; j < 8; ++j) { z0[j] = __builtin_inff(); z1[j] = __builtin_inff(); }

  float4 cur = mc4[b4];
  for (int i = 0; i < 64; ++i) {
    float4 nxt = mc4[b4 + ((i + 1) & 63)];
    float smA = smcalc(cur.x, cur.y);
    float smB = smcalc(cur.z, cur.w);
#pragma unroll
    for (int j = 0; j < 8; ++j) {
      float dA = dcalc2(px[j], py[j], sp[j], cur.x, cur.y, smA);
      z1[j] = MED3(z0[j], dA, z1[j]); z0[j] = fminf(z0[j], dA);
      float dB = dcalc2(px[j], py[j], sp[j], cur.z, cur.w, smB);
      z1[j] = MED3(z0[j], dB, z1[j]); z0[j] = fminf(z0[j], dB);
    }
    cur = nxt;
  }
#pragma unroll
  for (int j = 0; j < 8; ++j) {
    tv[(g * 8 + j) * 130 + s * 2 + 0] = z0[j];
    tv[(g * 8 + j) * 130 + s * 2 + 1] = z1[j];
  }
  __syncthreads();

  // ---- T_est per query: exact 16th smallest of 128 retained values
  if (t < 32) {
    float ch[16];
#pragma unroll
    for (int j = 0; j < 16; ++j) ch[j] = __builtin_inff();
    for (int k = 0; k < 128; ++k) {
      float v = tv[t * 130 + k];
#pragma unroll
      for (int j = 15; j >= 1; --j) ch[j] = MED3(ch[j-1], v, ch[j]);
      ch[0] = fminf(ch[0], v);
    }
    tstS[t] = ch[15];
    qcnt[t] = 0;
  }
  __syncthreads();
  float Tq[8];
#pragma unroll
  for (int j = 0; j < 8; ++j) Tq[j] = tstS[g * 8 + j];
  __syncthreads();                    // tv reads done; safe to overlay

  // ---- pass 2: collect candidates (unordered, dedup-free by construction)
  u16* qcand = (u16*)tv;              // 32 x 64 u16 = 4 KB overlay
  for (int i = 0; i < 64; ++i) {
    float4 c2 = mc4[b4 + i];
    float smA = smcalc(c2.x, c2.y);
    float smB = smcalc(c2.z, c2.w);
    const int idxA = basePt + 2 * i;
#pragma unroll
    for (int j = 0; j < 8; ++j) {
      float dA = dcalc2(px[j], py[j], sp[j], c2.x, c2.y, smA);
      if (dA <= Tq[j]) {
        int o = atomicAdd(&qcnt[g * 8 + j], 1);
        if (o < 64) qcand[(g * 8 + j) * 64 + o] = (u16)idxA;
      }
      float dB = dcalc2(px[j], py[j], sp[j], c2.z, c2.w, smB);
      if (dB <= Tq[j]) {
        int o = atomicAdd(&qcnt[g * 8 + j], 1);
        if (o < 64) qcand[(g * 8 + j) * 64 + o] = (u16)(idxA + 1);
      }
    }
  }
  __syncthreads();

  // ---- final: exact top-16 by (d asc, idx asc), 1 thread/query
  if (t < 32) {
    const int q = q0 + t;
    float2 p = pos[q];
    const float sq = spcalc(p.x, p.y);
    int cnt = qcnt[t]; if (cnt > 64) cnt = 64;
    float fd[16]; int fi[16];
#pragma unroll
    for (int j = 0; j < 16; ++j) { fd[j] = __builtin_inff(); fi[j] = 0x7fffffff; }
    for (int j = 0; j < cnt; ++j) {
      int ci = qcand[t * 64 + j];
      float2 m = mc[ci];
      float d = dcalc(p.x, p.y, sq, m.x, m.y);
      bool cc = (d < fd[15]) || (d == fd[15] && ci < fi[15]);
      if (cc) {
#pragma unroll
        for (int k = 15; k >= 1; --k) {
          bool cm = (d < fd[k-1]) || (d == fd[k-1] && ci < fi[k-1]);
          if (cc) {
            if (cm) { fd[k] = fd[k-1]; fi[k] = fi[k-1]; }
            else    { fd[k] = d;       fi[k] = ci;      }
          }
          cc = cm;
        }
        if (cc) { fd[0] = d; fi[0] = ci; }
      }
    }
    float* orow = knn_out + (size_t)q * 66;   // fp32 output 1 (knn_feat)
    u16*   xrow = X0 + (size_t)q * 96;        // bf16 MLP input, Kpad=96
    orow[0] = p.x; orow[1] = p.y;
    xrow[0] = f2bf(p.x); xrow[1] = f2bf(p.y);
#pragma unroll
    for (int j = 0; j < 16; ++j) {
      int ci = fi[j];
      float2 m = mc[ci], v = mv[ci];
      orow[2 + 4*j + 0] = m.x; orow[2 + 4*j + 1] = m.y;
      orow[2 + 4*j + 2] = v.x; orow[2 + 4*j + 3] = v.y;
      xrow[2 + 4*j + 0] = f2bf(m.x); xrow[2 + 4*j + 1] = f2bf(m.y);
      xrow[2 + 4*j + 2] = f2bf(v.x); xrow[2 + 4*j + 3] = f2bf(v.y);
    }
#pragma unroll
    for (int c = 66; c < 96; ++c) xrow[c] = 0;
  }
}

// ---------- weight prep: fp32 [K][N] -> bf16 transposed [N][Kpad] ----------
__global__ __launch_bounds__(256)
void prep_wt_all(const float* __restrict__ w1, const float* __restrict__ w2,
                 const float* __restrict__ w3, const float* __restrict__ w4,
                 const float* __restrict__ w5,
                 u16* __restrict__ wt1, u16* __restrict__ wt2, u16* __restrict__ wt3,
                 u16* __restrict__ wt4, u16* __restrict__ wt5)
{
  const int l = blockIdx.y;
  const float* w; u16* wt; int K, N, Kp;
  if (l == 0)      { w = w1; wt = wt1; K = 66;  N = 128; Kp = 96;  }
  else if (l == 1) { w = w2; wt = wt2; K = 128; N = 256; Kp = 128; }
  else if (l == 2) { w = w3; wt = wt3; K = 256; N = 512; Kp = 256; }
  else if (l == 3) { w = w4; wt = wt4; K = 512; N = 128; Kp = 512; }
  else             { w = w5; wt = wt5; K = 128; N = 64;  Kp = 128; }
  int i = blockIdx.x * 256 + threadIdx.x;
  if (i >= N * Kp) return;
  int n = i / Kp, kp = i - n * Kp;
  float v = (kp < K) ? w[(size_t)kp * N + n] : 0.0f;
  wt[i] = f2bf(v);
}

// ---------- GEMM (bf16 MFMA) + optional fused BN+ReLU on A + bias + stats ----------
template<int BN, bool FUSE>
__global__ __launch_bounds__(256)
void gemm_bn_kernel(const u16* __restrict__ X, int Kw,
                    const u16* __restrict__ WT,
                    const float* __restrict__ bias,
                    const float* __restrict__ psum, const float* __restrict__ psq,
                    const float* __restrict__ gw,   const float* __restrict__ bw,
                    u16* __restrict__ Z, int N,
                    float* __restrict__ csum, float* __restrict__ csq)
{
  constexpr int BM = 128;
  constexpr int AST = 40;                 // 32 data + 8 pad (bf16)
  __shared__ u16 Ash[BM * AST];
  __shared__ u16 Bsh[BN * AST];
  __shared__ float redS[4][128];
  __shared__ float redQ[4][128];
  __shared__ float scA[512];
  __shared__ float ttA[512];

  const int t = threadIdx.x;
  const int wave = t >> 6;
  const int lane = t & 63;
  const int lr = lane & 15;
  const int qd = lane >> 4;
  const int m0 = blockIdx.x * BM;
  const int n0 = blockIdx.y * BN;

  if (FUSE) {
    const float invB = 1.0f / 32768.0f;
    for (int c = t; c < Kw; c += 256) {
      float mean = psum[c] * invB;
      float var  = __fmaf_rn(-mean, mean, psq[c] * invB);  // biased
      float sc   = gw[c] * rsqrtf(var + EPS_BN);
      scA[c] = sc;
      ttA[c] = __fmaf_rn(-mean, sc, bw[c]);
    }
    __syncthreads();
  }

  f32x4 acc[2][BN / 16];
#pragma unroll
  for (int a = 0; a < 2; ++a)
#pragma unroll
    for (int b = 0; b < BN / 16; ++b) {
      acc[a][b][0] = 0.f; acc[a][b][1] = 0.f; acc[a][b][2] = 0.f; acc[a][b][3] = 0.f;
    }

  const int sr = t >> 2;          // 0..63
  const int sk = (t & 3) * 8;     // 0,8,16,24

  for (int k0 = 0; k0 < Kw; k0 += 32) {
#pragma unroll
    for (int rr = 0; rr < 2; ++rr) {
      int r = sr + rr * 64;
      uint4 g = *(const uint4*)(&X[(size_t)(m0 + r) * Kw + k0 + sk]);
      if (FUSE) {
        u32 w[4] = {g.x, g.y, g.z, g.w};
        u32 o[4];
#pragma unroll
        for (int e = 0; e < 4; ++e) {
          int kk = k0 + sk + 2 * e;
          float lo = bf2f((u16)(w[e] & 0xffffu));
          float hi = bf2f((u16)(w[e] >> 16));
          float yl = fmaxf(__fmaf_rn(lo, scA[kk],     ttA[kk]),     0.0f);
          float yh = fmaxf(__fmaf_rn(hi, scA[kk + 1], ttA[kk + 1]), 0.0f);
          o[e] = (u32)f2bf(yl) | ((u32)f2bf(yh) << 16);
        }
        g.x = o[0]; g.y = o[1]; g.z = o[2]; g.w = o[3];
      }
      *(uint4*)(&Ash[r * AST + sk]) = g;
    }
#pragma unroll
    for (int rr = 0; rr < BN / 64; ++rr) {
      int n = sr + rr * 64;
      *(uint4*)(&Bsh[n * AST + sk]) =
          *(const uint4*)(&WT[(size_t)(n0 + n) * Kw + k0 + sk]);
    }
    __syncthreads();
    bf16x8 af0 = *(const bf16x8*)(&Ash[(wave * 32 + lr) * AST + qd * 8]);
    bf16x8 af1 = *(const bf16x8*)(&Ash[(wave * 32 + 16 + lr) * AST + qd * 8]);
#pragma unroll
    for (int ct = 0; ct < BN / 16; ++ct) {
      bf16x8 bfr = *(const bf16x8*)(&Bsh[(ct * 16 + lr) * AST + qd * 8]);
      acc[0][ct] = __builtin_amdgcn_mfma_f32_16x16x32_bf16(af0, bfr, acc[0][ct], 0, 0, 0);
      acc[1][ct] = __builtin_amdgcn_mfma_f32_16x16x32_bf16(af1, bfr, acc[1][ct], 0, 0, 0);
    }
    __syncthreads();
  }

  // epilogue: bias, bf16 Z store, per-column partial sums
#pragma unroll
  for (int ct = 0; ct < BN / 16; ++ct) {
    int cg = n0 + ct * 16 + lr;
    float bv = bias[cg];
    float s = 0.f, sqv = 0.f;
#pragma unroll
    for (int rt = 0; rt < 2; ++rt) {
#pragma unroll
      for (int r = 0; r < 4; ++r) {
        float z = acc[rt][ct][r] + bv;
        int row = m0 + wave * 32 + rt * 16 + qd * 4 + r;  // C/D: row=quad*4+reg, col=lane&15
        Z[(size_t)row * N + cg] = f2bf(z);
        s += z;
        sqv = __fmaf_rn(z, z, sqv);
      }
    }
    s   += __shfl_xor(s, 16);   s   += __shfl_xor(s, 32);
    sqv += __shfl_xor(sqv, 16); sqv += __shfl_xor(sqv, 32);
    if (qd == 0) { redS[wave][ct * 16 + lr] = s; redQ[wave][ct * 16 + lr] = sqv; }
  }
  __syncthreads();
  if (t < BN) {
    float s  = redS[0][t] + redS[1][t] + redS[2][t] + redS[3][t];
    float sv = redQ[0][t] + redQ[1][t] + redQ[2][t] + redQ[3][t];
    atomicAdd(&csum[n0 + t], s);
    atomicAdd(&csq[n0 + t], sv);
  }
}

// ---------- final layer: fused BN5+ReLU + 64->2 GEMV, fp32 out ----------
__global__ __launch_bounds__(256)
void gemv6_kernel(const u16* __restrict__ Z5, const float* __restrict__ w6,
                  const float* __restrict__ b6,
                  const float* __restrict__ psum, const float* __restrict__ psq,
                  const float* __restrict__ gw,   const float* __restrict__ bw,
                  float* __restrict__ out)
{
  __shared__ float wsh[128];
  __shared__ float scs[64];
  __shared__ float tts[64];
  const int t = threadIdx.x;
  if (t < 128) wsh[t] = w6[t];
  if (t < 64) {
    const float invB = 1.0f / 32768.0f;
    float mean = psum[t] * invB;
    float var  = __fmaf_rn(-mean, mean, psq[t] * invB);
    float sc   = gw[t] * rsqrtf(var + EPS_BN);
    scs[t] = sc;
    tts[t] = __fmaf_rn(-mean, sc, bw[t]);
  }
  __syncthreads();
  const int q = blockIdx.x * 256 + t;
  const uint4* xv = (const uint4*)(Z5 + (size_t)q * 64);
  float a0 = 0.f, a1 = 0.f;
#pragma unroll
  for (int cc = 0; cc < 8; ++cc) {
    uint4 pk = xv[cc];
    u32 u[4] = {pk.x, pk.y, pk.z, pk.w};
#pragma unroll
    for (int uu = 0; uu < 4; ++uu) {
      int k = cc * 8 + uu * 2;
      float z0 = bf2f((u16)(u[uu] & 0xffffu));
      float z1 = bf2f((u16)(u[uu] >> 16));
      float x0 = fmaxf(__fmaf_rn(z0, scs[k],     tts[k]),     0.0f);
      float x1 = fmaxf(__fmaf_rn(z1, scs[k + 1], tts[k + 1]), 0.0f);
      x0 = bf2f(f2bf(x0));  // match prior bf16 round-trip of activations
      x1 = bf2f(f2bf(x1));
      a0 = __fmaf_rn(x0, wsh[2 * k + 0], a0);
      a1 = __fmaf_rn(x0, wsh[2 * k + 1], a1);
      a0 = __fmaf_rn(x1, wsh[2 * k + 2], a0);
      a1 = __fmaf_rn(x1, wsh[2 * k + 3], a1);
    }
  }
  float2 o; o.x = a0 + b6[0]; o.y = a1 + b6[1];
  ((float2*)out)[q] = o;
}

// ---------- launch ----------
extern "C" void kernel_launch(void* const* d_in, const int* in_sizes, int n_in,
                              void* d_out, int out_size, void* d_ws, size_t ws_size,
                              hipStream_t stream)
{
  const float2* pos = (const float2*)d_in[0];
  const float2* mc  = (const float2*)d_in[1];
  const float2* mv  = (const float2*)d_in[2];
  const float* w1 = (const float*)d_in[3];  const float* b1 = (const float*)d_in[4];
  const float* w2 = (const float*)d_in[5];  const float* b2 = (const float*)d_in[6];
  const float* w3 = (const float*)d_in[7];  const float* b3 = (const float*)d_in[8];
  const float* w4 = (const float*)d_in[9];  const float* b4 = (const float*)d_in[10];
  const float* w5 = (const float*)d_in[11]; const float* b5 = (const float*)d_in[12];
  const float* w6 = (const float*)d_in[13]; const float* b6 = (const float*)d_in[14];
  const float* g1 = (const float*)d_in[15]; const float* be1 = (const float*)d_in[16];
  const float* g2 = (const float*)d_in[17]; const float* be2 = (const float*)d_in[18];
  const float* g3 = (const float*)d_in[19]; const float* be3 = (const float*)d_in[20];
  const float* g4 = (const float*)d_in[21]; const float* be4 = (const float*)d_in[22];
  const float* g5 = (const float*)d_in[23]; const float* be5 = (const float*)d_in[24];

  // ws layout (bf16): X0 6.29MB | ZA 33.55MB | ZB 33.55MB | WT1..5 | stats
  char* ws = (char*)d_ws;
  u16* X0   = (u16*)(ws + 0);
  u16* ZA   = (u16*)(ws + 6291456);
  u16* ZB   = (u16*)(ws + 39845888);
  u16* WT1  = (u16*)(ws + 73400320);
  u16* WT2  = (u16*)(ws + 73424896);
  u16* WT3  = (u16*)(ws + 73490432);
  u16* WT4  = (u16*)(ws + 73752576);
  u16* WT5  = (u16*)(ws + 73883648);
  float* stats = (float*)(ws + 73900032);
  float* s1 = stats;        float* s2 = stats + 128;  float* s3 = stats + 384;
  float* s4 = stats + 896;  float* s5 = stats + 1024;
  float* sqb = stats + 1088;
  float* q1 = sqb;          float* q2 = sqb + 128;    float* q3 = sqb + 384;
  float* q4 = sqb + 896;    float* q5 = sqb + 1024;

  float* outX = (float*)d_out;
  float* outK = outX + 2 * B_ROWS;

  hipMemsetAsync(stats, 0, 2176 * sizeof(float), stream);
  prep_wt_all<<<dim3(512, 5), 256, 0, stream>>>(w1, w2, w3, w4, w5, WT1, WT2, WT3, WT4, WT5);
  knn_kernel<<<dim3(1024), 256, 0, stream>>>(pos, mc, mv, outK, X0);

  gemm_bn_kernel<128, false><<<dim3(256, 1), 256, 0, stream>>>(
      X0, 96, WT1, b1, nullptr, nullptr, nullptr, nullptr, ZA, 128, s1, q1);
  gemm_bn_kernel<128, true><<<dim3(256, 2), 256, 0, stream>>>(
      ZA, 128, WT2, b2, s1, q1, g1, be1, ZB, 256, s2, q2);
  gemm_bn_kernel<128, true><<<dim3(256, 4), 256, 0, stream>>>(
      ZB, 256, WT3, b3, s2, q2, g2, be2, ZA, 512, s3, q3);
  gemm_bn_kernel<128, true><<<dim3(256, 1), 256, 0, stream>>>(
      ZA, 512, WT4, b4, s3, q3, g3, be3, ZB, 128, s4, q4);
  gemm_bn_kernel<64, true><<<dim3(256, 1), 256, 0, stream>>>(
      ZB, 128, WT5, b5, s4, q4, g4, be4, ZA, 64, s5, q5);
  gemv6_kernel<<<dim3(128), 256, 0, stream>>>(ZA, w6, b6, s5, q5, g5, be5, outX);

  (void)in_sizes; (void)n_in; (void)out_size; (void)ws_size;
}

// Round 14
// 358.569 us; speedup vs baseline: 2.9751x; 1.0155x over previous
//
#include <hip/hip_runtime.h>

typedef unsigned short u16;
typedef unsigned int   u32;
typedef __attribute__((ext_vector_type(8))) short bf16x8;
typedef __attribute__((ext_vector_type(4))) float f32x4;

#define B_ROWS 32768
#define EPS_BN 1e-5f

// ---------- helpers ----------
__device__ __forceinline__ u16 f2bf(float f) {
  u32 u = __float_as_uint(f);
  u32 r = (u + 0x7FFFu + ((u >> 16) & 1u)) >> 16;   // RNE, no NaN inputs
  return (u16)r;
}
__device__ __forceinline__ float bf2f(u16 h) {
  return __uint_as_float(((u32)h) << 16);
}

// GENUINE numpy-fp32 emulation — contraction disabled (critical fix, R9):
//   sp = RN(RN(px^2)+RN(py^2)); sm = RN(RN(mx^2)+RN(my^2))   [no fma]
//   dot = fma(py,my, RN(px*mx));  d2 = RN(RN(sp+sm) - 2*dot)
__device__ __forceinline__ float dcalc(float px, float py, float sp, float mx, float my) {
#pragma clang fp contract(off)
  float sm   = mx * mx + my * my;
  float pm   = px * mx;
  float dot  = __builtin_fmaf(py, my, pm);
  float spsm = sp + sm;
  return spsm - 2.0f * dot;
}
// same bits, with sm precomputed once per point (sm expression identical)
__device__ __forceinline__ float dcalc2(float px, float py, float sp, float mx, float my,
                                        float sm) {
#pragma clang fp contract(off)
  float pm   = px * mx;
  float dot  = __builtin_fmaf(py, my, pm);
  float spsm = sp + sm;
  return spsm - 2.0f * dot;
}
__device__ __forceinline__ float smcalc(float mx, float my) {
#pragma clang fp contract(off)
  return mx * mx + my * my;
}
__device__ __forceinline__ float spcalc(float px, float py) {
#pragma clang fp contract(off)
  return px * px + py * py;
}
#define MED3 __builtin_amdgcn_fmed3f

// ---------- KNN: 32 queries/block, 8 queries/thread x 128-pt slice ----------
__global__ __launch_bounds__(256, 4)
void knn_kernel(const float2* __restrict__ pos, const float2* __restrict__ mc,
                const float2* __restrict__ mv, float* __restrict__ knn_out,
                u16* __restrict__ X0)
{
  __shared__ float tv[32 * 130];      // 16.6 KB retained values [q][s*2+v], pad->130
  __shared__ float tstS[32];
  __shared__ int   qcnt[32];

  const int t = threadIdx.x;
  const int g = t >> 6;               // wave = query group (8 queries)
  const int s = t & 63;               // slice id: 128 points
  const int q0 = blockIdx.x * 32;

  float px[8], py[8], sp[8];
#pragma unroll
  for (int j = 0; j < 8; ++j) {
    float2 p = pos[q0 + g * 8 + j];
    px[j] = p.x; py[j] = p.y; sp[j] = spcalc(p.x, p.y);
  }

  const float4* mc4 = (const float4*)mc;
  const int b4 = s * 64;              // 64 float4 = 128 points
  const int basePt = s * 128;

  // ---- pass 1: top-2 chain per query
  float z0[8], z1[8];
#pragma unroll
  for (int j = 0; j < 8; ++j) { z0[j] = __builtin_inff(); z1[j] = __builtin_inff(); }

  float4 cur = mc4[b4];
  for (int i = 0; i < 64; ++i) {
    float4 nxt = mc4[b4 + ((i + 1) & 63)];
    float smA = smcalc(cur.x, cur.y);
    float smB = smcalc(cur.z, cur.w);
#pragma unroll
    for (int j = 0; j < 8; ++j) {
      float dA = dcalc2(px[j], py[j], sp[j], cur.x, cur.y, smA);
      z1[j] = MED3(z0[j], dA, z1[j]); z0[j] = fminf(z0[j], dA);
      float dB = dcalc2(px[j], py[j], sp[j], cur.z, cur.w, smB);
      z1[j] = MED3(z0[j], dB, z1[j]); z0[j] = fminf(z0[j], dB);
    }
    cur = nxt;
  }
#pragma unroll
  for (int j = 0; j < 8; ++j) {
    tv[(g * 8 + j) * 130 + s * 2 + 0] = z0[j];
    tv[(g * 8 + j) * 130 + s * 2 + 1] = z1[j];
  }
  __syncthreads();

  // ---- T_est per query: exact 16th smallest of 128 retained values
  if (t < 32) {
    float ch[16];
#pragma unroll
    for (int j = 0; j < 16; ++j) ch[j] = __builtin_inff();
    for (int k = 0; k < 128; ++k) {
      float v = tv[t * 130 + k];
#pragma unroll
      for (int j = 15; j >= 1; --j) ch[j] = MED3(ch[j-1], v, ch[j]);
      ch[0] = fminf(ch[0], v);
    }
    tstS[t] = ch[15];
    qcnt[t] = 0;
  }
  __syncthreads();
  float Tq[8];
#pragma unroll
  for (int j = 0; j < 8; ++j) Tq[j] = tstS[g * 8 + j];
  __syncthreads();                    // tv reads done; safe to overlay

  // ---- pass 2: collect candidates (unordered)
  u16* qcand = (u16*)tv;              // 32 x 64 u16 = 4 KB overlay
  for (int i = 0; i < 64; ++i) {
    float4 c2 = mc4[b4 + i];
    float smA = smcalc(c2.x, c2.y);
    float smB = smcalc(c2.z, c2.w);
    const int idxA = basePt + 2 * i;
#pragma unroll
    for (int j = 0; j < 8; ++j) {
      float dA = dcalc2(px[j], py[j], sp[j], c2.x, c2.y, smA);
      if (dA <= Tq[j]) {
        int o = atomicAdd(&qcnt[g * 8 + j], 1);
        if (o < 64) qcand[(g * 8 + j) * 64 + o] = (u16)idxA;
      }
      float dB = dcalc2(px[j], py[j], sp[j], c2.z, c2.w, smB);
      if (dB <= Tq[j]) {
        int o = atomicAdd(&qcnt[g * 8 + j], 1);
        if (o < 64) qcand[(g * 8 + j) * 64 + o] = (u16)(idxA + 1);
      }
    }
  }
  __syncthreads();

  // ---- final: exact top-16 by (d asc, idx asc), 1 thread/query
  if (t < 32) {
    const int q = q0 + t;
    float2 p = pos[q];
    const float sq = spcalc(p.x, p.y);
    int cnt = qcnt[t]; if (cnt > 64) cnt = 64;
    float fd[16]; int fi[16];
#pragma unroll
    for (int j = 0; j < 16; ++j) { fd[j] = __builtin_inff(); fi[j] = 0x7fffffff; }
    for (int j = 0; j < cnt; ++j) {
      int ci = qcand[t * 64 + j];
      float2 m = mc[ci];
      float d = dcalc(p.x, p.y, sq, m.x, m.y);
      bool cc = (d < fd[15]) || (d == fd[15] && ci < fi[15]);
      if (cc) {
#pragma unroll
        for (int k = 15; k >= 1; --k) {
          bool cm = (d < fd[k-1]) || (d == fd[k-1] && ci < fi[k-1]);
          if (cc) {
            if (cm) { fd[k] = fd[k-1]; fi[k] = fi[k-1]; }
            else    { fd[k] = d;       fi[k] = ci;      }
          }
          cc = cm;
        }
        if (cc) { fd[0] = d; fi[0] = ci; }
      }
    }
    float* orow = knn_out + (size_t)q * 66;   // fp32 output 1 (knn_feat)
    u16*   xrow = X0 + (size_t)q * 96;        // bf16 MLP input, Kpad=96
    orow[0] = p.x; orow[1] = p.y;
    xrow[0] = f2bf(p.x); xrow[1] = f2bf(p.y);
#pragma unroll
    for (int j = 0; j < 16; ++j) {
      int ci = fi[j];
      float2 m = mc[ci], v = mv[ci];
      orow[2 + 4*j + 0] = m.x; orow[2 + 4*j + 1] = m.y;
      orow[2 + 4*j + 2] = v.x; orow[2 + 4*j + 3] = v.y;
      xrow[2 + 4*j + 0] = f2bf(m.x); xrow[2 + 4*j + 1] = f2bf(m.y);
      xrow[2 + 4*j + 2] = f2bf(v.x); xrow[2 + 4*j + 3] = f2bf(v.y);
    }
#pragma unroll
    for (int c = 66; c < 96; ++c) xrow[c] = 0;
  }
}

// ---------- weight prep: fp32 [K][N] -> bf16 transposed [N][Kpad] ----------
__global__ __launch_bounds__(256)
void prep_wt_all(const float* __restrict__ w1, const float* __restrict__ w2,
                 const float* __restrict__ w3, const float* __restrict__ w4,
                 const float* __restrict__ w5,
                 u16* __restrict__ wt1, u16* __restrict__ wt2, u16* __restrict__ wt3,
                 u16* __restrict__ wt4, u16* __restrict__ wt5)
{
  const int l = blockIdx.y;
  const float* w; u16* wt; int K, N, Kp;
  if (l == 0)      { w = w1; wt = wt1; K = 66;  N = 128; Kp = 96;  }
  else if (l == 1) { w = w2; wt = wt2; K = 128; N = 256; Kp = 128; }
  else if (l == 2) { w = w3; wt = wt3; K = 256; N = 512; Kp = 256; }
  else if (l == 3) { w = w4; wt = wt4; K = 512; N = 128; Kp = 512; }
  else             { w = w5; wt = wt5; K = 128; N = 64;  Kp = 128; }
  int i = blockIdx.x * 256 + threadIdx.x;
  if (i >= N * Kp) return;
  int n = i / Kp, kp = i - n * Kp;
  float v = (kp < K) ? w[(size_t)kp * N + n] : 0.0f;
  wt[i] = f2bf(v);
}

// ---------- GEMM (bf16 MFMA, BM=128 x BN) + fused BN+ReLU on A + bias + stats ----------
template<int BN, bool FUSE>
__global__ __launch_bounds__(256)
void gemm_bn_kernel(const u16* __restrict__ X, int Kw,
                    const u16* __restrict__ WT,
                    const float* __restrict__ bias,
                    const float* __restrict__ psum, const float* __restrict__ psq,
                    const float* __restrict__ gw,   const float* __restrict__ bw,
                    u16* __restrict__ Z, int N,
                    float* __restrict__ csum, float* __restrict__ csq)
{
  constexpr int BM = 128;
  constexpr int AST = 40;                 // 32 data + 8 pad (bf16)
  __shared__ u16 Ash[BM * AST];
  __shared__ u16 Bsh[BN * AST];
  __shared__ float redS[4][BN];
  __shared__ float redQ[4][BN];
  __shared__ float scA[512];
  __shared__ float ttA[512];

  const int t = threadIdx.x;
  const int wave = t >> 6;
  const int lane = t & 63;
  const int lr = lane & 15;
  const int qd = lane >> 4;
  const int m0 = blockIdx.x * BM;
  const int n0 = blockIdx.y * BN;

  if (FUSE) {
    const float invB = 1.0f / 32768.0f;
    for (int c = t; c < Kw; c += 256) {
      float mean = psum[c] * invB;
      float var  = __fmaf_rn(-mean, mean, psq[c] * invB);  // biased
      float sc   = gw[c] * rsqrtf(var + EPS_BN);
      scA[c] = sc;
      ttA[c] = __fmaf_rn(-mean, sc, bw[c]);
    }
    __syncthreads();
  }

  f32x4 acc[2][BN / 16];
#pragma unroll
  for (int a = 0; a < 2; ++a)
#pragma unroll
    for (int b = 0; b < BN / 16; ++b) {
      acc[a][b][0] = 0.f; acc[a][b][1] = 0.f; acc[a][b][2] = 0.f; acc[a][b][3] = 0.f;
    }

  const int sr = t >> 2;          // 0..63
  const int sk = (t & 3) * 8;     // 0,8,16,24

  for (int k0 = 0; k0 < Kw; k0 += 32) {
#pragma unroll
    for (int rr = 0; rr < 2; ++rr) {
      int r = sr + rr * 64;
      uint4 g = *(const uint4*)(&X[(size_t)(m0 + r) * Kw + k0 + sk]);
      if (FUSE) {
        u32 w[4] = {g.x, g.y, g.z, g.w};
        u32 o[4];
#pragma unroll
        for (int e = 0; e < 4; ++e) {
          int kk = k0 + sk + 2 * e;
          float lo = bf2f((u16)(w[e] & 0xffffu));
          float hi = bf2f((u16)(w[e] >> 16));
          float yl = fmaxf(__fmaf_rn(lo, scA[kk],     ttA[kk]),     0.0f);
          float yh = fmaxf(__fmaf_rn(hi, scA[kk + 1], ttA[kk + 1]), 0.0f);
          o[e] = (u32)f2bf(yl) | ((u32)f2bf(yh) << 16);
        }
        g.x = o[0]; g.y = o[1]; g.z = o[2]; g.w = o[3];
      }
      *(uint4*)(&Ash[r * AST + sk]) = g;
    }
    if (BN == 128) {
#pragma unroll
      for (int rr = 0; rr < 2; ++rr) {
        int n = sr + rr * 64;
        *(uint4*)(&Bsh[n * AST + sk]) =
            *(const uint4*)(&WT[(size_t)(n0 + n) * Kw + k0 + sk]);
      }
    } else {                          // BN == 64
      int n = sr;
      *(uint4*)(&Bsh[n * AST + sk]) =
          *(const uint4*)(&WT[(size_t)(n0 + n) * Kw + k0 + sk]);
    }
    __syncthreads();
    bf16x8 af0 = *(const bf16x8*)(&Ash[(wave * 32 + lr) * AST + qd * 8]);
    bf16x8 af1 = *(const bf16x8*)(&Ash[(wave * 32 + 16 + lr) * AST + qd * 8]);
#pragma unroll
    for (int ct = 0; ct < BN / 16; ++ct) {
      bf16x8 bfr = *(const bf16x8*)(&Bsh[(ct * 16 + lr) * AST + qd * 8]);
      acc[0][ct] = __builtin_amdgcn_mfma_f32_16x16x32_bf16(af0, bfr, acc[0][ct], 0, 0, 0);
      acc[1][ct] = __builtin_amdgcn_mfma_f32_16x16x32_bf16(af1, bfr, acc[1][ct], 0, 0, 0);
    }
    __syncthreads();
  }

  // epilogue: bias, bf16 Z store, per-column partial sums
#pragma unroll
  for (int ct = 0; ct < BN / 16; ++ct) {
    int cg = n0 + ct * 16 + lr;
    float bv = bias[cg];
    float s = 0.f, sqv = 0.f;
#pragma unroll
    for (int rt = 0; rt < 2; ++rt) {
#pragma unroll
      for (int r = 0; r < 4; ++r) {
        float z = acc[rt][ct][r] + bv;
        int row = m0 + wave * 32 + rt * 16 + qd * 4 + r;  // C/D: row=quad*4+reg, col=lane&15
        Z[(size_t)row * N + cg] = f2bf(z);
        s += z;
        sqv = __fmaf_rn(z, z, sqv);
      }
    }
    s   += __shfl_xor(s, 16);   s   += __shfl_xor(s, 32);
    sqv += __shfl_xor(sqv, 16); sqv += __shfl_xor(sqv, 32);
    if (qd == 0) { redS[wave][ct * 16 + lr] = s; redQ[wave][ct * 16 + lr] = sqv; }
  }
  __syncthreads();
  if (t < BN) {
    float s  = redS[0][t] + redS[1][t] + redS[2][t] + redS[3][t];
    float sv = redQ[0][t] + redQ[1][t] + redQ[2][t] + redQ[3][t];
    atomicAdd(&csum[n0 + t], s);
    atomicAdd(&csq[n0 + t], sv);
  }
}

// ---------- final layer: fused BN5+ReLU + 64->2 GEMV, fp32 out ----------
__global__ __launch_bounds__(256)
void gemv6_kernel(const u16* __restrict__ Z5, const float* __restrict__ w6,
                  const float* __restrict__ b6,
                  const float* __restrict__ psum, const float* __restrict__ psq,
                  const float* __restrict__ gw,   const float* __restrict__ bw,
                  float* __restrict__ out)
{
  __shared__ float wsh[128];
  __shared__ float scs[64];
  __shared__ float tts[64];
  const int t = threadIdx.x;
  if (t < 128) wsh[t] = w6[t];
  if (t < 64) {
    const float invB = 1.0f / 32768.0f;
    float mean = psum[t] * invB;
    float var  = __fmaf_rn(-mean, mean, psq[t] * invB);
    float sc   = gw[t] * rsqrtf(var + EPS_BN);
    scs[t] = sc;
    tts[t] = __fmaf_rn(-mean, sc, bw[t]);
  }
  __syncthreads();
  const int q = blockIdx.x * 256 + t;
  const uint4* xv = (const uint4*)(Z5 + (size_t)q * 64);
  float a0 = 0.f, a1 = 0.f;
#pragma unroll
  for (int cc = 0; cc < 8; ++cc) {
    uint4 pk = xv[cc];
    u32 u[4] = {pk.x, pk.y, pk.z, pk.w};
#pragma unroll
    for (int uu = 0; uu < 4; ++uu) {
      int k = cc * 8 + uu * 2;
      float z0 = bf2f((u16)(u[uu] & 0xffffu));
      float z1 = bf2f((u16)(u[uu] >> 16));
      float x0 = fmaxf(__fmaf_rn(z0, scs[k],     tts[k]),     0.0f);
      float x1 = fmaxf(__fmaf_rn(z1, scs[k + 1], tts[k + 1]), 0.0f);
      x0 = bf2f(f2bf(x0));  // match prior bf16 round-trip of activations
      x1 = bf2f(f2bf(x1));
      a0 = __fmaf_rn(x0, wsh[2 * k + 0], a0);
      a1 = __fmaf_rn(x0, wsh[2 * k + 1], a1);
      a0 = __fmaf_rn(x1, wsh[2 * k + 2], a0);
      a1 = __fmaf_rn(x1, wsh[2 * k + 3], a1);
    }
  }
  float2 o; o.x = a0 + b6[0]; o.y = a1 + b6[1];
  ((float2*)out)[q] = o;
}

// ---------- launch ----------
extern "C" void kernel_launch(void* const* d_in, const int* in_sizes, int n_in,
                              void* d_out, int out_size, void* d_ws, size_t ws_size,
                              hipStream_t stream)
{
  const float2* pos = (const float2*)d_in[0];
  const float2* mc  = (const float2*)d_in[1];
  const float2* mv  = (const float2*)d_in[2];
  const float* w1 = (const float*)d_in[3];  const float* b1 = (const float*)d_in[4];
  const float* w2 = (const float*)d_in[5];  const float* b2 = (const float*)d_in[6];
  const float* w3 = (const float*)d_in[7];  const float* b3 = (const float*)d_in[8];
  const float* w4 = (const float*)d_in[9];  const float* b4 = (const float*)d_in[10];
  const float* w5 = (const float*)d_in[11]; const float* b5 = (const float*)d_in[12];
  const float* w6 = (const float*)d_in[13]; const float* b6 = (const float*)d_in[14];
  const float* g1 = (const float*)d_in[15]; const float* be1 = (const float*)d_in[16];
  const float* g2 = (const float*)d_in[17]; const float* be2 = (const float*)d_in[18];
  const float* g3 = (const float*)d_in[19]; const float* be3 = (const float*)d_in[20];
  const float* g4 = (const float*)d_in[21]; const float* be4 = (const float*)d_in[22];
  const float* g5 = (const float*)d_in[23]; const float* be5 = (const float*)d_in[24];

  // ws layout (bf16): X0 6.29MB | ZA 33.55MB | ZB 33.55MB | WT1..5 | stats
  char* ws = (char*)d_ws;
  u16* X0   = (u16*)(ws + 0);
  u16* ZA   = (u16*)(ws + 6291456);
  u16* ZB   = (u16*)(ws + 39845888);
  u16* WT1  = (u16*)(ws + 73400320);
  u16* WT2  = (u16*)(ws + 73424896);
  u16* WT3  = (u16*)(ws + 73490432);
  u16* WT4  = (u16*)(ws + 73752576);
  u16* WT5  = (u16*)(ws + 73883648);
  float* stats = (float*)(ws + 73900032);
  float* s1 = stats;        float* s2 = stats + 128;  float* s3 = stats + 384;
  float* s4 = stats + 896;  float* s5 = stats + 1024;
  float* sqb = stats + 1088;
  float* q1 = sqb;          float* q2 = sqb + 128;    float* q3 = sqb + 384;
  float* q4 = sqb + 896;    float* q5 = sqb + 1024;

  float* outX = (float*)d_out;
  float* outK = outX + 2 * B_ROWS;

  hipMemsetAsync(stats, 0, 2176 * sizeof(float), stream);
  prep_wt_all<<<dim3(512, 5), 256, 0, stream>>>(w1, w2, w3, w4, w5, WT1, WT2, WT3, WT4, WT5);
  knn_kernel<<<dim3(1024), 256, 0, stream>>>(pos, mc, mv, outK, X0);

  // BN=64 tiles everywhere: 2-8 blocks/CU instead of 1-4
  gemm_bn_kernel<64, false><<<dim3(256, 2), 256, 0, stream>>>(
      X0, 96, WT1, b1, nullptr, nullptr, nullptr, nullptr, ZA, 128, s1, q1);
  gemm_bn_kernel<64, true><<<dim3(256, 4), 256, 0, stream>>>(
      ZA, 128, WT2, b2, s1, q1, g1, be1, ZB, 256, s2, q2);
  gemm_bn_kernel<64, true><<<dim3(256, 8), 256, 0, stream>>>(
      ZB, 256, WT3, b3, s2, q2, g2, be2, ZA, 512, s3, q3);
  gemm_bn_kernel<64, true><<<dim3(256, 2), 256, 0, stream>>>(
      ZA, 512, WT4, b4, s3, q3, g3, be3, ZB, 128, s4, q4);
  gemm_bn_kernel<64, true><<<dim3(256, 1), 256, 0, stream>>>(
      ZB, 128, WT5, b5, s4, q4, g4, be4, ZA, 64, s5, q5);
  gemv6_kernel<<<dim3(128), 256, 0, stream>>>(ZA, w6, b6, s5, q5, g5, be5, outX);

  (void)in_sizes; (void)n_in; (void)out_size; (void)ws_size;
}